// Round 5
// baseline (1479.921 us; speedup 1.0000x reference)
//
#include <hip/hip_runtime.h>
#include <math.h>

// Problem constants
#define PVOX 110592   // 48*48*48
#define CDIM 128
#define EDIM 512

typedef __attribute__((ext_vector_type(8))) short short8_t;
typedef __attribute__((ext_vector_type(4))) float float4_t;

__device__ __forceinline__ unsigned short f2bf(float f) {
  unsigned int u = __float_as_uint(f);
  unsigned int r = (u + 0x7FFFu + ((u >> 16) & 1u)) >> 16;  // RNE
  return (unsigned short)r;
}
__device__ __forceinline__ float bf2f(unsigned short s) {
  return __uint_as_float(((unsigned int)s) << 16);
}
// XOR-swizzled bf16 tile layout: row-major stride 128, 8-elem chunks permuted.
__device__ __forceinline__ int swz(int row, int col) {
  return (row << 7) + ((((col >> 3) ^ (row & 15)) << 3) | (col & 7));
}
// fp32 output tile [c][p], stride 128, word-level XOR swizzle
__device__ __forceinline__ int swzO(int c, int p) {
  return (c << 7) + (p ^ ((c & 15) << 2));
}

// ---------------- K0: weight prep (transpose + bf16 cast) ----------------
__global__ __launch_bounds__(256) void k0_wprep(
    const float* __restrict__ w1, const float* __restrict__ w2,
    unsigned short* __restrict__ w1t, unsigned short* __restrict__ w2t) {
  int idx = blockIdx.x * 256 + threadIdx.x;  // 0..65535
  int e = idx >> 7, c = idx & 127;
  w1t[e * 128 + c] = f2bf(w1[c * 512 + e]);  // w1t[e][c]  (B^T for pw1)
  w2t[c * 512 + e] = f2bf(w2[e * 128 + c]);  // w2t[c][e]  (B^T for pw2)
}

// ---------------- K1: depthwise 7x7x7 conv + bias (NCDHW fp32) ----------------
// v5 = v3's rolling-depth register-ring engine (read each plane from LDS once,
// weights via wave-uniform scalar loads — the 48-VGPR no-spill variant) with
// an occupancy retile: block = (b, c, 12-d quarter, 16-h third), 192 threads
// (16h x 12 w-quads). LDS = one 22-row x 60-word plane, double-buffered =
// 10.6 KB -> 10+ blocks/CU co-resident (v3's grid of 512 left each CU with
// effectively ONE 9-wave block; its barriers/load waits were fully exposed).
// Grid 3072. Ring depth 7; iters = 18 planes per block for 12 outputs.
template <bool GUARD>
__device__ __forceinline__ void conv_plane12(
    const float* __restrict__ bufr, const float* __restrict__ wbase,
    float (&acc)[7][4], int hl, int w0, int q) {
#pragma unroll
  for (int kh = 0; kh < 7; kh++) {
    const float* rp = &bufr[(hl + kh) * 60 + w0];
    float4_t v0 = *(const float4_t*)&rp[0];
    float4_t v1 = *(const float4_t*)&rp[4];
    float4_t v2 = *(const float4_t*)&rp[8];
    float v[12] = {v0[0], v0[1], v0[2], v0[3], v1[0], v1[1], v1[2], v1[3],
                   v2[0], v2[1], v2[2], v2[3]};
#pragma unroll
    for (int kd = 0; kd < 7; kd++) {
      if (!GUARD || (unsigned)(q - kd) < 12u) {
        const float* wr = wbase + kd * 49 + kh * 7;
#pragma unroll
        for (int kw = 0; kw < 7; kw++) {
          float wv = wr[kw];
#pragma unroll
          for (int wi = 0; wi < 4; wi++)
            acc[6 - kd][wi] += wv * v[wi + kw + 1];
        }
      }
    }
  }
}

__global__ __launch_bounds__(192) void k1_dwconv(
    const float* __restrict__ x, const float* __restrict__ dw_w,
    const float* __restrict__ dw_b, float* __restrict__ yconv) {
  __shared__ float sx[2][22 * 60];  // 10.6 KB
  int bx = blockIdx.x;
  int h3 = bx % 3;
  int dt4 = (bx / 3) & 3;
  int c = (bx / 12) & 127;
  int b = bx / 1536;
  int dt0 = dt4 * 12, h0 = h3 * 16;
  const float* xp = x + (size_t)(b * 128 + c) * PVOX;
  float* yp = yconv + (size_t)(b * 128 + c) * PVOX;
  const float* wbase = dw_w + c * 343;  // wave-uniform -> scalar loads
  float bias = dw_b[c];
  int t = threadIdx.x;
  int hl = t / 12, wq = t % 12;   // compute mapping: 16h x 12 w-quads
  int w0 = wq * 4;
  // staging mapping: granule A = (row hl, wq); granule B (t<72) = (row hl+16, wq)
  // zero both buffers: pads (w cols 0..3 and 52..59) stay zero forever; OOB
  // h rows are re-written as zeros every stage.
  for (int i = t; i < 2 * 22 * 60; i += 192) ((float*)sx)[i] = 0.f;
  __syncthreads();
  // prologue stage: plane dt0-3 into buf 0 (only valid for dt4>0)
  {
    int p = dt0 - 3;
    if (p >= 0) {
      {
        int gh = h0 - 3 + hl;
        float4_t v = {0.f, 0.f, 0.f, 0.f};
        if ((unsigned)gh < 48u)
          v = *(const float4_t*)&xp[((size_t)p * 48 + gh) * 48 + wq * 4];
        *(float4_t*)&sx[0][hl * 60 + 4 + wq * 4] = v;
      }
      if (t < 72) {
        int gh = h0 + 13 + hl;
        float4_t v = {0.f, 0.f, 0.f, 0.f};
        if ((unsigned)gh < 48u)
          v = *(const float4_t*)&xp[((size_t)p * 48 + gh) * 48 + wq * 4];
        *(float4_t*)&sx[0][(hl + 16) * 60 + 4 + wq * 4] = v;
      }
    }
  }
  float acc[7][4];
#pragma unroll
  for (int j = 0; j < 7; j++)
#pragma unroll
    for (int i = 0; i < 4; i++) acc[j][i] = bias;
  __syncthreads();

  // ---- prologue: q in [0,6) — guarded consume, no write-out ----
  for (int q = 0; q < 6; ++q) {
    int p = dt0 - 3 + q, pn = p + 1;
    bool ok = (pn >= 0);  // pn <= 47 and pn <= dt0+14 automatic here
    float4_t sA = {0.f, 0.f, 0.f, 0.f}, sB = {0.f, 0.f, 0.f, 0.f};
    if (ok) {
      int gh = h0 - 3 + hl;
      if ((unsigned)gh < 48u)
        sA = *(const float4_t*)&xp[((size_t)pn * 48 + gh) * 48 + wq * 4];
      if (t < 72) {
        int gh2 = h0 + 13 + hl;
        if ((unsigned)gh2 < 48u)
          sB = *(const float4_t*)&xp[((size_t)pn * 48 + gh2) * 48 + wq * 4];
      }
    }
    if (p >= 0)
      conv_plane12<true>(sx[q & 1], wbase, acc, hl, w0, q);
#pragma unroll
    for (int j = 0; j < 6; j++)
#pragma unroll
      for (int i = 0; i < 4; i++) acc[j][i] = acc[j + 1][i];
#pragma unroll
    for (int i = 0; i < 4; i++) acc[6][i] = bias;
    float* bw = (float*)sx[(q + 1) & 1];
    *(float4_t*)&bw[hl * 60 + 4 + wq * 4] = sA;
    if (t < 72) *(float4_t*)&bw[(hl + 16) * 60 + 4 + wq * 4] = sB;
    __syncthreads();
  }
  // ---- steady: q in [6,12) — branch-free ----
  for (int q = 6; q < 12; ++q) {
    int pn = dt0 - 2 + q;  // in [dt0+4, dt0+9] subset of [4,45]: always valid
    float4_t sA, sB = {0.f, 0.f, 0.f, 0.f};
    {
      int gh = h0 - 3 + hl;
      float4_t v = {0.f, 0.f, 0.f, 0.f};
      if ((unsigned)gh < 48u)
        v = *(const float4_t*)&xp[((size_t)pn * 48 + gh) * 48 + wq * 4];
      sA = v;
      if (t < 72) {
        int gh2 = h0 + 13 + hl;
        if ((unsigned)gh2 < 48u)
          sB = *(const float4_t*)&xp[((size_t)pn * 48 + gh2) * 48 + wq * 4];
      }
    }
    conv_plane12<false>(sx[q & 1], wbase, acc, hl, w0, q);
    {
      int d = dt0 + q - 6;
      float4_t o;
      o[0] = acc[0][0]; o[1] = acc[0][1]; o[2] = acc[0][2]; o[3] = acc[0][3];
      *(float4_t*)&yp[((size_t)d * 48 + (h0 + hl)) * 48 + w0] = o;
    }
#pragma unroll
    for (int j = 0; j < 6; j++)
#pragma unroll
      for (int i = 0; i < 4; i++) acc[j][i] = acc[j + 1][i];
#pragma unroll
    for (int i = 0; i < 4; i++) acc[6][i] = bias;
    float* bw = (float*)sx[(q + 1) & 1];
    *(float4_t*)&bw[hl * 60 + 4 + wq * 4] = sA;
    if (t < 72) *(float4_t*)&bw[(hl + 16) * 60 + 4 + wq * 4] = sB;
    __syncthreads();
  }
  // ---- epilogue: q in [12,18) — guarded ----
  for (int q = 12; q < 18; ++q) {
    int p = dt0 - 3 + q, pn = p + 1;
    bool ok = (pn <= 47) && (pn <= dt0 + 14);  // pn >= 0 automatic
    float4_t sA = {0.f, 0.f, 0.f, 0.f}, sB = {0.f, 0.f, 0.f, 0.f};
    if (ok) {
      int gh = h0 - 3 + hl;
      if ((unsigned)gh < 48u)
        sA = *(const float4_t*)&xp[((size_t)pn * 48 + gh) * 48 + wq * 4];
      if (t < 72) {
        int gh2 = h0 + 13 + hl;
        if ((unsigned)gh2 < 48u)
          sB = *(const float4_t*)&xp[((size_t)pn * 48 + gh2) * 48 + wq * 4];
      }
    }
    if (p <= 47)
      conv_plane12<true>(sx[q & 1], wbase, acc, hl, w0, q);
    {
      int d = dt0 + q - 6;
      float4_t o;
      o[0] = acc[0][0]; o[1] = acc[0][1]; o[2] = acc[0][2]; o[3] = acc[0][3];
      *(float4_t*)&yp[((size_t)d * 48 + (h0 + hl)) * 48 + w0] = o;
    }
#pragma unroll
    for (int j = 0; j < 6; j++)
#pragma unroll
      for (int i = 0; i < 4; i++) acc[j][i] = acc[j + 1][i];
#pragma unroll
    for (int i = 0; i < 4; i++) acc[6][i] = bias;
    float* bw = (float*)sx[(q + 1) & 1];
    *(float4_t*)&bw[hl * 60 + 4 + wq * 4] = sA;
    if (t < 72) *(float4_t*)&bw[(hl + 16) * 60 + 4 + wq * 4] = sB;
    __syncthreads();
  }
}

// ---------------- K2: LayerNorm over C + transpose to channels-last bf16 ----------------
__global__ __launch_bounds__(256) void k2_ln(
    const float* __restrict__ yconv, const float* __restrict__ ln_g,
    const float* __restrict__ ln_b, unsigned short* __restrict__ ycl) {
  __shared__ float sy[128 * 65];  // stride 65 breaks bank conflicts
  __shared__ float smean[64], srstd[64];
  int bx = blockIdx.x;
  int b = bx / 1728;
  int p0 = (bx % 1728) * 64;
  int t = threadIdx.x;
  int v = t & 63, c4 = t >> 6;
  const float* yp = yconv + (size_t)b * 128 * PVOX + p0;
  for (int cc = 0; cc < 32; cc++) {
    int c = cc * 4 + c4;
    sy[c * 65 + v] = yp[(size_t)c * PVOX + v];
  }
  __syncthreads();
  if (t < 64) {
    float s = 0.f, ss = 0.f;
    for (int c = 0; c < 128; c++) { float val = sy[c * 65 + t]; s += val; ss += val * val; }
    float mu = s * (1.f / 128.f);
    float var = ss * (1.f / 128.f) - mu * mu;
    smean[t] = mu; srstd[t] = rsqrtf(var + 1e-6f);
  }
  __syncthreads();
  unsigned short* op = ycl + ((size_t)b * PVOX + p0) * 128;
  for (int it = 0; it < 32; it++) {
    int idx = it * 256 + t;
    int vv = idx >> 7, c = idx & 127;
    float val = (sy[c * 65 + vv] - smean[vv]) * srstd[vv] * ln_g[c] + ln_b[c];
    op[vv * 128 + c] = f2bf(val);
  }
}

// ---------------- K3: pwconv1 (bf16 MFMA) + bias + GELU + GRN sumsq ----------------
// et-fused: one block per 128-voxel tile (grid 1728); A staged once, four
// e-tiles looped inside (stage B -> MFMA -> epilogue via sB -> copy out).
// Saves the 4x re-read of ycl (-170 MB HBM) and 3/4 of A staging work.
__global__ __launch_bounds__(256) void k3_pw1(
    const unsigned short* __restrict__ ycl, const unsigned short* __restrict__ w1t,
    const float* __restrict__ b1, unsigned short* __restrict__ h,
    float* __restrict__ gsum) {
  __shared__ short smem[2 * 128 * 128];  // 64 KB
  short* sA = smem;
  short* sB = smem + 128 * 128;
  int pt = blockIdx.x;   // 0..1727
  int b = (pt >= 864) ? 1 : 0;
  int t = threadIdx.x;
  for (int it = 0; it < 8; it++) {
    int flat = it * 2048 + t * 8;
    int row = flat >> 7, col = flat & 127;
    *(uint4*)&sA[swz(row, col)] = *(const uint4*)&ycl[((size_t)(pt * 128 + row)) * 128 + col];
  }
  int wave = t >> 6, lane = t & 63;
  int wm = (wave >> 1) * 64, wn = (wave & 1) * 64;
  int ln15 = lane & 15, q = lane >> 4;
  for (int et = 0; et < 4; et++) {
    int e0 = et << 7;
    for (int it = 0; it < 8; it++) {
      int flat = it * 2048 + t * 8;
      int row = flat >> 7, col = flat & 127;
      *(uint4*)&sB[swz(row, col)] = *(const uint4*)&w1t[(e0 + row) * 128 + col];
    }
    __syncthreads();  // B (and, for et=0, A) visible
    float4_t acc[4][4] = {};
    for (int kk = 0; kk < 4; kk++) {
      int k0 = kk * 32 + q * 8;
      short8_t af[4], bf[4];
#pragma unroll
      for (int i = 0; i < 4; i++)
        af[i] = *(const short8_t*)&sA[swz(wm + i * 16 + ln15, k0)];
#pragma unroll
      for (int j = 0; j < 4; j++)
        bf[j] = *(const short8_t*)&sB[swz(wn + j * 16 + ln15, k0)];
#pragma unroll
      for (int i = 0; i < 4; i++)
#pragma unroll
        for (int j = 0; j < 4; j++)
          acc[i][j] = __builtin_amdgcn_mfma_f32_16x16x32_bf16(af[i], bf[j], acc[i][j], 0, 0, 0);
    }
    __syncthreads();  // done reading sB; reuse it for the h-tile
    float biasv[4];
#pragma unroll
    for (int j = 0; j < 4; j++) biasv[j] = b1[e0 + wn + j * 16 + ln15];
    float ssq[4] = {0.f, 0.f, 0.f, 0.f};
#pragma unroll
    for (int i = 0; i < 4; i++) {
#pragma unroll
      for (int j = 0; j < 4; j++) {
        int e_local = wn + j * 16 + ln15;
#pragma unroll
        for (int r = 0; r < 4; r++) {
          float val = acc[i][j][r] + biasv[j];
          float g = 0.5f * val * (1.0f + erff(val * 0.70710678118f));
          ssq[j] += g * g;
          sB[swz(wm + i * 16 + q * 4 + r, e_local)] = (short)f2bf(g);
        }
      }
    }
#pragma unroll
    for (int j = 0; j < 4; j++) {
      ssq[j] += __shfl_xor(ssq[j], 16);
      ssq[j] += __shfl_xor(ssq[j], 32);
    }
    if (q == 0) {
#pragma unroll
      for (int j = 0; j < 4; j++)
        atomicAdd(&gsum[b * 512 + e0 + wn + j * 16 + ln15], ssq[j]);
    }
    __syncthreads();  // h-tile complete in sB
    for (int it = 0; it < 8; it++) {
      int flat = it * 2048 + t * 8;
      int row = flat >> 7, col = flat & 127;
      *(uint4*)&h[((size_t)(pt * 128 + row)) * 512 + e0 + col] = *(const uint4*)&sB[swz(row, col)];
    }
    __syncthreads();  // copy-out done before next et overwrites sB
  }
}

// ---------------- K4: GRN scalars ----------------
__global__ __launch_bounds__(512) void k4_grn(
    const float* __restrict__ gsum, const float* __restrict__ grn_g,
    const float* __restrict__ grn_b, const float* __restrict__ w2,
    const float* __restrict__ b2, float* __restrict__ s, float* __restrict__ badd) {
  __shared__ float red[512];
  int t = threadIdx.x;
  for (int b = 0; b < 2; b++) {
    float gx = sqrtf(gsum[b * 512 + t]);
    red[t] = gx;
    __syncthreads();
    for (int off = 256; off > 0; off >>= 1) {
      if (t < off) red[t] += red[t + off];
      __syncthreads();
    }
    float mean = red[0] * (1.f / 512.f);
    __syncthreads();
    s[b * 512 + t] = 1.0f + grn_g[t] * (gx / (mean + 1e-6f));
  }
  if (t < 128) {
    float acc = b2[t];
    for (int e = 0; e < 512; e++) acc += grn_b[e] * w2[e * 128 + t];
    badd[t] = acc;
  }
}

// ---------------- K5: pwconv2 (bf16 MFMA, K=512) + badd + residual ----------------
__global__ __launch_bounds__(256) void k5_pw2(
    const unsigned short* __restrict__ h, const unsigned short* __restrict__ w2t,
    const float* __restrict__ s, const float* __restrict__ badd,
    const float* __restrict__ x, float* __restrict__ out) {
  __shared__ short smem[2 * 128 * 128];  // 64 KB; reused as fp32 out-tile at end
  short* sA = smem;
  short* sB = smem + 128 * 128;
  int bx = blockIdx.x;           // 0..1727
  int b = bx / 864;
  int p0 = (bx % 864) * 128;
  int vp0 = bx * 128;
  int t = threadIdx.x;
  int wave = t >> 6, lane = t & 63;
  int wm = (wave >> 1) * 64, wn = (wave & 1) * 64;
  int ln15 = lane & 15, q = lane >> 4;
  const float* sb = s + b * 512;
  float4_t acc[4][4] = {};
  for (int ec = 0; ec < 4; ec++) {
    int e0 = ec * 128;
    for (int it = 0; it < 8; it++) {
      int flat = it * 2048 + t * 8;
      int row = flat >> 7, col = flat & 127;
      uint4 raw = *(const uint4*)&h[((size_t)(vp0 + row)) * 512 + e0 + col];
      const unsigned short* us = (const unsigned short*)&raw;
      unsigned short ov[8];
#pragma unroll
      for (int i2 = 0; i2 < 8; i2++)
        ov[i2] = f2bf(bf2f(us[i2]) * sb[e0 + col + i2]);
      *(uint4*)&sA[swz(row, col)] = *(const uint4*)ov;
      *(uint4*)&sB[swz(row, col)] = *(const uint4*)&w2t[row * 512 + e0 + col];  // row = c
    }
    __syncthreads();
    for (int kk = 0; kk < 4; kk++) {
      int k0 = kk * 32 + q * 8;
      short8_t af[4], bf[4];
#pragma unroll
      for (int i = 0; i < 4; i++)
        af[i] = *(const short8_t*)&sA[swz(wm + i * 16 + ln15, k0)];
#pragma unroll
      for (int j = 0; j < 4; j++)
        bf[j] = *(const short8_t*)&sB[swz(wn + j * 16 + ln15, k0)];
#pragma unroll
      for (int i = 0; i < 4; i++)
#pragma unroll
        for (int j = 0; j < 4; j++)
          acc[i][j] = __builtin_amdgcn_mfma_f32_16x16x32_bf16(af[i], bf[j], acc[i][j], 0, 0, 0);
    }
    __syncthreads();
  }
  float* sO = (float*)smem;
#pragma unroll
  for (int i = 0; i < 4; i++)
#pragma unroll
    for (int j = 0; j < 4; j++) {
      int c = wn + j * 16 + ln15;
#pragma unroll
      for (int r = 0; r < 4; r++)
        sO[swzO(c, wm + i * 16 + q * 4 + r)] = acc[i][j][r];
    }
  __syncthreads();
  for (int it = 0; it < 16; it++) {
    int flat4 = it * 256 + t;
    int c = flat4 >> 5, col4 = (flat4 & 31) * 4;
    float4_t v = *(const float4_t*)&sO[swzO(c, col4)];
    float bd = badd[c];
    size_t gi = (size_t)(b * 128 + c) * PVOX + p0 + col4;
    float4_t xv = *(const float4_t*)&x[gi];
    v[0] += bd + xv[0]; v[1] += bd + xv[1]; v[2] += bd + xv[2]; v[3] += bd + xv[3];
    *(float4_t*)&out[gi] = v;
  }
}

// ---------------- launch ----------------
extern "C" void kernel_launch(void* const* d_in, const int* in_sizes, int n_in,
                              void* d_out, int out_size, void* d_ws, size_t ws_size,
                              hipStream_t stream) {
  (void)in_sizes; (void)n_in; (void)out_size; (void)ws_size;
  const float* x    = (const float*)d_in[0];
  const float* dw_w = (const float*)d_in[1];
  const float* dw_b = (const float*)d_in[2];
  const float* ln_g = (const float*)d_in[3];
  const float* ln_b = (const float*)d_in[4];
  const float* w1   = (const float*)d_in[5];
  const float* b1   = (const float*)d_in[6];
  const float* grn_g= (const float*)d_in[7];
  const float* grn_b= (const float*)d_in[8];
  const float* w2   = (const float*)d_in[9];
  const float* b2   = (const float*)d_in[10];
  float* outp = (float*)d_out;

  char* w = (char*)d_ws;
  float*          yconv = (float*)(w);
  unsigned short* ycl   = (unsigned short*)(w + 113246208);
  unsigned short* h     = (unsigned short*)(w + 169869312);
  float*          gsum  = (float*)(w + 396361728);
  float*          s     = (float*)(w + 396365824);
  float*          badd  = (float*)(w + 396369920);
  unsigned short* w1t   = (unsigned short*)(w + 396370432);
  unsigned short* w2t   = (unsigned short*)(w + 396501504);

  hipMemsetAsync(gsum, 0, 2 * 512 * sizeof(float), stream);
  k0_wprep<<<256, 256, 0, stream>>>(w1, w2, w1t, w2t);
  k1_dwconv<<<3072, 192, 0, stream>>>(x, dw_w, dw_b, yconv);
  k2_ln<<<3456, 256, 0, stream>>>(yconv, ln_g, ln_b, ycl);
  k3_pw1<<<1728, 256, 0, stream>>>(ycl, w1t, b1, h, gsum);
  k4_grn<<<1, 512, 0, stream>>>(gsum, grn_g, grn_b, w2, b2, s, badd);
  k5_pw2<<<1728, 256, 0, stream>>>(h, w2t, s, badd, x, outp);
}